// Round 1
// baseline (129.939 us; speedup 1.0000x reference)
//
#include <hip/hip_runtime.h>

#define H_DIM 768
#define B_DIM 64
#define L_DIM 512
#define M_TOT (B_DIM*L_DIM)   // 32768
#define BM 128
#define BN 128
#define BK 64
#define NB_CNT (H_DIM/BN)     // 6
#define KB_CNT (H_DIM/BK)     // 12
#define TILE_HALFS (BM*BK)    // 8192 halfs = 16KB

typedef _Float16 f16x8 __attribute__((ext_vector_type(8)));
typedef float f32x4 __attribute__((ext_vector_type(4)));

// ws byte offsets
#define WS_W16   0u           // 768*768 halfs = 1179648 B (tiled, swizzle-baked)
#define WS_NUP   1179648u     // 6*32768 f32 = 786432 B
#define WS_ALPHA 1966080u     // 32768 f32
#define WS_POOL  2097152u     // 8*64*768 f32 = 1572864 B

__device__ __forceinline__ void gload_lds16(const void* g, void* l) {
  __builtin_amdgcn_global_load_lds((const __attribute__((address_space(1))) void*)g,
                                   (__attribute__((address_space(3))) void*)l, 16, 0, 0);
}

// ---------------- kernel 1: W_fc fp32 -> fp16, tiled + swizzle-baked ----------------
// Tile t = nb*KB_CNT + kb holds BN x BK halfs in LDS-image order:
//   image[row*BK + sp*8 + j] = W_fc[nb*BN+row][kb*BK + (sp^(row&7))*8 + j]
__global__ __launch_bounds__(256) void wconv_kernel(const float* __restrict__ Wfc,
                                                    _Float16* __restrict__ W16) {
  int t = blockIdx.x;             // 0..71
  int nb = t / KB_CNT, kb = t % KB_CNT;
  for (int i = 0; i < 4; ++i) {
    int u = threadIdx.x + i * 256;        // 0..1023 (row, phys slot)
    int row = u >> 3, sp = u & 7;
    int sl = sp ^ (row & 7);              // logical slot in K
    const float* src = Wfc + (size_t)(nb*BN + row)*H_DIM + kb*BK + sl*8;
    f32x4 x0 = *(const f32x4*)src;
    f32x4 x1 = *(const f32x4*)(src + 4);
    f16x8 h;
    h[0]=(_Float16)x0[0]; h[1]=(_Float16)x0[1]; h[2]=(_Float16)x0[2]; h[3]=(_Float16)x0[3];
    h[4]=(_Float16)x1[0]; h[5]=(_Float16)x1[1]; h[6]=(_Float16)x1[2]; h[7]=(_Float16)x1[3];
    *(f16x8*)(W16 + (size_t)t*TILE_HALFS + u*8) = h;
  }
}

// ---------------- kernel 2: GEMM + tanh + dot(W_nu) -> nu partials ----------------
// C[m,n] = sum_k A[m,k]*Wfc[n,k];  nu_part[nb][m] = sum_{n in block} tanh(C+b)*W_nu[n]
__global__ __launch_bounds__(256) void gemm_nu_kernel(const float* __restrict__ A,
                                                      const _Float16* __restrict__ W16,
                                                      const float* __restrict__ bfc,
                                                      const float* __restrict__ wnu,
                                                      float* __restrict__ nup) {
  __shared__ __align__(16) _Float16 lsA[TILE_HALFS];
  __shared__ __align__(16) _Float16 lsB[TILE_HALFS];
  __shared__ float nred[2][BM];

  int bid = blockIdx.x;
  int nb = bid % NB_CNT;
  int mb = bid / NB_CNT;
  int m0 = mb * BM, n0 = nb * BN;
  int tid = threadIdx.x;
  int wv = tid >> 6, ln = tid & 63;
  int wr = wv >> 1, wc = wv & 1;          // 2x2 wave grid, 64x64 each
  int lrow = ln & 15, lk = ln >> 4;

  f32x4 acc[4][4] = {};
  const _Float16* wbase = W16 + (size_t)(nb * KB_CNT) * TILE_HALFS;

  for (int kb = 0; kb < KB_CNT; ++kb) {
    // stage B: linear global_load_lds from pre-swizzled image (wave base + lane*16)
    const _Float16* wt = wbase + (size_t)kb * TILE_HALFS;
    for (int i = 0; i < 4; ++i) {
      int e = i*2048 + wv*512 + ln*8;     // halfs; bytes = i*4096 + wv*1024 + ln*16
      gload_lds16(wt + e, lsB + e);
    }
    // stage A: fp32 load -> fp16 -> swizzled ds_write_b128
    for (int i = 0; i < 4; ++i) {
      int u = tid + i * 256;
      int row = u >> 3, sl = u & 7;       // iterate logical slots (coalesced global)
      const float* src = A + (size_t)(m0 + row) * H_DIM + kb*BK + sl*8;
      f32x4 x0 = *(const f32x4*)src;
      f32x4 x1 = *(const f32x4*)(src + 4);
      f16x8 h;
      h[0]=(_Float16)x0[0]; h[1]=(_Float16)x0[1]; h[2]=(_Float16)x0[2]; h[3]=(_Float16)x0[3];
      h[4]=(_Float16)x1[0]; h[5]=(_Float16)x1[1]; h[6]=(_Float16)x1[2]; h[7]=(_Float16)x1[3];
      *(f16x8*)(lsA + row*BK + ((sl ^ (row & 7)) * 8)) = h;
    }
    __syncthreads();
    for (int kk = 0; kk < 2; ++kk) {
      f16x8 af[4], bf[4];
      int s = kk*4 + lk;
      for (int mi = 0; mi < 4; ++mi) {
        int r = wr*64 + mi*16 + lrow;
        af[mi] = *(const f16x8*)(lsA + r*BK + ((s ^ (r & 7)) * 8));
      }
      for (int ni = 0; ni < 4; ++ni) {
        int r = wc*64 + ni*16 + lrow;
        bf[ni] = *(const f16x8*)(lsB + r*BK + ((s ^ (r & 7)) * 8));
      }
      for (int mi = 0; mi < 4; ++mi)
        for (int ni = 0; ni < 4; ++ni)
          acc[mi][ni] = __builtin_amdgcn_mfma_f32_16x16x32_f16(af[mi], bf[ni], acc[mi][ni], 0, 0, 0);
    }
    __syncthreads();
  }

  // epilogue: tanh(acc+b)*wnu, reduce over this block's 128 n-columns
  float wn[4], bb[4];
  for (int ni = 0; ni < 4; ++ni) {
    int c = n0 + wc*64 + ni*16 + lrow;    // C/D col = lane&15 (m89-verified)
    wn[ni] = wnu[c];
    bb[ni] = bfc[c];
  }
  for (int mi = 0; mi < 4; ++mi) {
    for (int r = 0; r < 4; ++r) {
      float s = 0.f;
      for (int ni = 0; ni < 4; ++ni) {
        float v = acc[mi][ni][r] + bb[ni];
        float e = __expf(2.0f * v);
        s += (1.0f - 2.0f / (e + 1.0f)) * wn[ni];   // tanh(v)
      }
      // reduce across the 16 lanes sharing this output row
      for (int o = 1; o < 16; o <<= 1) s += __shfl_xor(s, o, 64);
      if (lrow == 0) nred[wc][wr*64 + mi*16 + lk*4 + r] = s;  // row = (lane>>4)*4+reg
    }
  }
  __syncthreads();
  if (tid < BM)
    nup[(size_t)nb * M_TOT + m0 + tid] = nred[0][tid] + nred[1][tid];
}

// ---------------- kernel 3: softmax over L per batch ----------------
__global__ __launch_bounds__(512) void softmax_kernel(const float* __restrict__ nup,
                                                      float* __restrict__ alphas) {
  int b = blockIdx.x;
  int l = threadIdx.x;
  int m = b * L_DIM + l;
  float v = 0.f;
  for (int nb = 0; nb < NB_CNT; ++nb) v += nup[(size_t)nb * M_TOT + m];
  __shared__ float smax[8], ssum[8];
  int w = l >> 6, ln = l & 63;
  float mx = v;
  for (int o = 1; o < 64; o <<= 1) mx = fmaxf(mx, __shfl_xor(mx, o, 64));
  if (ln == 0) smax[w] = mx;
  __syncthreads();
  mx = smax[0];
  for (int i = 1; i < 8; ++i) mx = fmaxf(mx, smax[i]);
  float e = __expf(v - mx);
  float sm = e;
  for (int o = 1; o < 64; o <<= 1) sm += __shfl_xor(sm, o, 64);
  if (ln == 0) ssum[w] = sm;
  __syncthreads();
  float tot = 0.f;
  for (int i = 0; i < 8; ++i) tot += ssum[i];
  alphas[m] = e / tot;
}

// ---------------- kernel 4/5: weighted pooling (deterministic 2-stage) ----------------
__global__ __launch_bounds__(256) void pool1_kernel(const float* __restrict__ hs,
                                                    const float* __restrict__ alphas,
                                                    float* __restrict__ part) {
  int b = blockIdx.x >> 3;
  int lc = blockIdx.x & 7;                 // 8 chunks of 64 rows
  int tid = threadIdx.x;
  __shared__ float al[64];
  if (tid < 64) al[tid] = alphas[b * L_DIM + lc*64 + tid];
  __syncthreads();
  const float* xp = hs + ((size_t)b * L_DIM + lc*64) * H_DIM;
  int h0 = tid * 3;                        // 768 = 256*3, contiguous 12B per lane
  float s0 = 0.f, s1 = 0.f, s2 = 0.f;
  for (int l = 0; l < 64; ++l) {
    float a = al[l];
    const float* r = xp + (size_t)l * H_DIM + h0;
    s0 += a * r[0]; s1 += a * r[1]; s2 += a * r[2];
  }
  float* dst = part + ((size_t)lc * B_DIM + b) * H_DIM + h0;
  dst[0] = s0; dst[1] = s1; dst[2] = s2;
}

__global__ __launch_bounds__(256) void pool2_kernel(const float* __restrict__ part,
                                                    float* __restrict__ out) {
  int i = blockIdx.x * 256 + threadIdx.x;  // < 49152
  float s = 0.f;
  for (int lc = 0; lc < 8; ++lc) s += part[(size_t)lc * (B_DIM * H_DIM) + i];
  out[i] = s;
}

extern "C" void kernel_launch(void* const* d_in, const int* in_sizes, int n_in,
                              void* d_out, int out_size, void* d_ws, size_t ws_size,
                              hipStream_t stream) {
  const float* hs  = (const float*)d_in[0];
  const float* Wfc = (const float*)d_in[1];
  const float* bfc = (const float*)d_in[2];
  const float* wnu = (const float*)d_in[3];
  float* out = (float*)d_out;
  char* ws = (char*)d_ws;
  _Float16* W16 = (_Float16*)(ws + WS_W16);
  float* nup    = (float*)(ws + WS_NUP);
  float* alphas = (float*)(ws + WS_ALPHA);
  float* part   = (float*)(ws + WS_POOL);

  wconv_kernel<<<NB_CNT * KB_CNT, 256, 0, stream>>>(Wfc, W16);
  gemm_nu_kernel<<<(M_TOT / BM) * NB_CNT, 256, 0, stream>>>(hs, W16, bfc, wnu, nup);
  softmax_kernel<<<B_DIM, 512, 0, stream>>>(nup, alphas);
  pool1_kernel<<<B_DIM * 8, 256, 0, stream>>>(hs, alphas, part);
  pool2_kernel<<<192, 256, 0, stream>>>(part, out);
}

// Round 2
// 112.290 us; speedup vs baseline: 1.1572x; 1.1572x over previous
//
#include <hip/hip_runtime.h>

#define H_DIM 768
#define B_DIM 64
#define L_DIM 512
#define M_TOT (B_DIM*L_DIM)   // 32768
#define BM 128
#define BN 128
#define BK 64
#define NB_CNT (H_DIM/BN)     // 6
#define KB_CNT (H_DIM/BK)     // 12
#define MB_CNT (M_TOT/BM)     // 256
#define TILE_HALFS (BM*BK)    // 8192 halfs = 16KB

typedef _Float16 f16x8 __attribute__((ext_vector_type(8)));
typedef float f32x4 __attribute__((ext_vector_type(4)));

// ws byte offsets
#define WS_W16   0u           // 768*768 halfs = 1179648 B (tiled, swizzle-baked)
#define WS_NUP   1179648u     // 6*32768 f32 = 786432 B
#define WS_ALPHA 1966080u     // 32768 f32
#define WS_POOL  2097152u     // 8*64*768 f32 = 1572864 B
#define WS_AIMG  3670016u     // 32768*768 halfs = 50331648 B (tiled, swizzle-baked)
#define WS_NEED_IMG (WS_AIMG + (size_t)M_TOT*H_DIM*2)

__device__ __forceinline__ void gload_lds16(const void* g, void* l) {
  __builtin_amdgcn_global_load_lds((const __attribute__((address_space(1))) void*)g,
                                   (__attribute__((address_space(3))) void*)l, 16, 0, 0);
}

__device__ __forceinline__ f16x8 cvt8(const float* src) {
  f32x4 x0 = *(const f32x4*)src;
  f32x4 x1 = *(const f32x4*)(src + 4);
  f16x8 h;
  h[0]=(_Float16)x0[0]; h[1]=(_Float16)x0[1]; h[2]=(_Float16)x0[2]; h[3]=(_Float16)x0[3];
  h[4]=(_Float16)x1[0]; h[5]=(_Float16)x1[1]; h[6]=(_Float16)x1[2]; h[7]=(_Float16)x1[3];
  return h;
}

// ---------------- kernel 1: W_fc fp32 -> fp16, tiled + swizzle-baked ----------------
// Tile t = nb*KB_CNT + kb holds BN x BK halfs in LDS-image order:
//   image[row*BK + sp*8 + j] = W_fc[nb*BN+row][kb*BK + (sp^(row&7))*8 + j]
__global__ __launch_bounds__(256) void wconv_kernel(const float* __restrict__ Wfc,
                                                    _Float16* __restrict__ W16) {
  int t = blockIdx.x;             // 0..71
  int nb = t / KB_CNT, kb = t % KB_CNT;
  for (int i = 0; i < 4; ++i) {
    int u = threadIdx.x + i * 256;        // (row, phys slot)
    int row = u >> 3, sp = u & 7;
    int sl = sp ^ (row & 7);
    *(f16x8*)(W16 + (size_t)t*TILE_HALFS + u*8) =
        cvt8(Wfc + (size_t)(nb*BN + row)*H_DIM + kb*BK + sl*8);
  }
}

// ---------------- kernel 1b: hidden_states fp32 -> fp16 tiled image ----------------
// Tile t = mb*KB_CNT + kb, same image layout as W tiles.
__global__ __launch_bounds__(256) void aconv_kernel(const float* __restrict__ A,
                                                    _Float16* __restrict__ img) {
  int t = blockIdx.x;             // 0..3071
  int mb = t / KB_CNT, kb = t % KB_CNT;
  _Float16* tile = img + (size_t)t * TILE_HALFS;
  for (int i = 0; i < 4; ++i) {
    int u = threadIdx.x + i * 256;
    int row = u >> 3, sp = u & 7;
    int sl = sp ^ (row & 7);
    *(f16x8*)(tile + u*8) =
        cvt8(A + (size_t)(mb*BM + row)*H_DIM + kb*BK + sl*8);
  }
}

// ---------------- kernel 2: GEMM + tanh + dot(W_nu) -> nu partials ----------------
// Both operands staged via global_load_lds from pre-swizzled images.
__global__ __launch_bounds__(256) void gemm_nu_img_kernel(const _Float16* __restrict__ Aimg,
                                                          const _Float16* __restrict__ W16,
                                                          const float* __restrict__ bfc,
                                                          const float* __restrict__ wnu,
                                                          float* __restrict__ nup) {
  __shared__ __align__(16) _Float16 lsA[TILE_HALFS];
  __shared__ __align__(16) _Float16 lsB[TILE_HALFS];
  __shared__ float nred[2][BM];

  int bid = blockIdx.x;
  int mb = bid & (MB_CNT - 1);    // all CUs sweep one nb-pass together -> A-image L3 reuse
  int nb = bid >> 8;
  int m0 = mb * BM, n0 = nb * BN;
  int tid = threadIdx.x;
  int wv = tid >> 6, ln = tid & 63;
  int wr = wv >> 1, wc = wv & 1;
  int lrow = ln & 15, lk = ln >> 4;

  f32x4 acc[4][4] = {};
  const _Float16* abase = Aimg + (size_t)(mb * KB_CNT) * TILE_HALFS;
  const _Float16* wbase = W16 + (size_t)(nb * KB_CNT) * TILE_HALFS;

  for (int kb = 0; kb < KB_CNT; ++kb) {
    const _Float16* at = abase + (size_t)kb * TILE_HALFS;
    const _Float16* wt = wbase + (size_t)kb * TILE_HALFS;
    for (int i = 0; i < 4; ++i) {
      int e = i*2048 + wv*512 + ln*8;     // bytes = i*4096 + wv*1024 + ln*16
      gload_lds16(at + e, lsA + e);
      gload_lds16(wt + e, lsB + e);
    }
    __syncthreads();
    for (int kk = 0; kk < 2; ++kk) {
      f16x8 af[4], bf[4];
      int s = kk*4 + lk;
      for (int mi = 0; mi < 4; ++mi) {
        int r = wr*64 + mi*16 + lrow;
        af[mi] = *(const f16x8*)(lsA + r*BK + ((s ^ (r & 7)) * 8));
      }
      for (int ni = 0; ni < 4; ++ni) {
        int r = wc*64 + ni*16 + lrow;
        bf[ni] = *(const f16x8*)(lsB + r*BK + ((s ^ (r & 7)) * 8));
      }
      for (int mi = 0; mi < 4; ++mi)
        for (int ni = 0; ni < 4; ++ni)
          acc[mi][ni] = __builtin_amdgcn_mfma_f32_16x16x32_f16(af[mi], bf[ni], acc[mi][ni], 0, 0, 0);
    }
    __syncthreads();
  }

  float wn[4], bb[4];
  for (int ni = 0; ni < 4; ++ni) {
    int c = n0 + wc*64 + ni*16 + lrow;    // C/D col = lane&15
    wn[ni] = wnu[c];
    bb[ni] = bfc[c];
  }
  for (int mi = 0; mi < 4; ++mi) {
    for (int r = 0; r < 4; ++r) {
      float s = 0.f;
      for (int ni = 0; ni < 4; ++ni) {
        float v = acc[mi][ni][r] + bb[ni];
        float e = __expf(2.0f * v);
        s += (1.0f - 2.0f / (e + 1.0f)) * wn[ni];   // tanh(v)
      }
      for (int o = 1; o < 16; o <<= 1) s += __shfl_xor(s, o, 64);
      if (lrow == 0) nred[wc][wr*64 + mi*16 + lk*4 + r] = s;  // row = (lane>>4)*4+reg
    }
  }
  __syncthreads();
  if (tid < BM)
    nup[(size_t)nb * M_TOT + m0 + tid] = nred[0][tid] + nred[1][tid];
}

// ---------------- fallback GEMM (fp32 A, in-kernel convert) ----------------
__global__ __launch_bounds__(256) void gemm_nu_kernel(const float* __restrict__ A,
                                                      const _Float16* __restrict__ W16,
                                                      const float* __restrict__ bfc,
                                                      const float* __restrict__ wnu,
                                                      float* __restrict__ nup) {
  __shared__ __align__(16) _Float16 lsA[TILE_HALFS];
  __shared__ __align__(16) _Float16 lsB[TILE_HALFS];
  __shared__ float nred[2][BM];

  int bid = blockIdx.x;
  int nb = bid % NB_CNT;
  int mb = bid / NB_CNT;
  int m0 = mb * BM, n0 = nb * BN;
  int tid = threadIdx.x;
  int wv = tid >> 6, ln = tid & 63;
  int wr = wv >> 1, wc = wv & 1;
  int lrow = ln & 15, lk = ln >> 4;

  f32x4 acc[4][4] = {};
  const _Float16* wbase = W16 + (size_t)(nb * KB_CNT) * TILE_HALFS;

  for (int kb = 0; kb < KB_CNT; ++kb) {
    const _Float16* wt = wbase + (size_t)kb * TILE_HALFS;
    for (int i = 0; i < 4; ++i) {
      int e = i*2048 + wv*512 + ln*8;
      gload_lds16(wt + e, lsB + e);
    }
    for (int i = 0; i < 4; ++i) {
      int u = tid + i * 256;
      int row = u >> 3, sl = u & 7;
      *(f16x8*)(lsA + row*BK + ((sl ^ (row & 7)) * 8)) =
          cvt8(A + (size_t)(m0 + row) * H_DIM + kb*BK + sl*8);
    }
    __syncthreads();
    for (int kk = 0; kk < 2; ++kk) {
      f16x8 af[4], bf[4];
      int s = kk*4 + lk;
      for (int mi = 0; mi < 4; ++mi) {
        int r = wr*64 + mi*16 + lrow;
        af[mi] = *(const f16x8*)(lsA + r*BK + ((s ^ (r & 7)) * 8));
      }
      for (int ni = 0; ni < 4; ++ni) {
        int r = wc*64 + ni*16 + lrow;
        bf[ni] = *(const f16x8*)(lsB + r*BK + ((s ^ (r & 7)) * 8));
      }
      for (int mi = 0; mi < 4; ++mi)
        for (int ni = 0; ni < 4; ++ni)
          acc[mi][ni] = __builtin_amdgcn_mfma_f32_16x16x32_f16(af[mi], bf[ni], acc[mi][ni], 0, 0, 0);
    }
    __syncthreads();
  }

  float wn[4], bb[4];
  for (int ni = 0; ni < 4; ++ni) {
    int c = n0 + wc*64 + ni*16 + lrow;
    wn[ni] = wnu[c];
    bb[ni] = bfc[c];
  }
  for (int mi = 0; mi < 4; ++mi) {
    for (int r = 0; r < 4; ++r) {
      float s = 0.f;
      for (int ni = 0; ni < 4; ++ni) {
        float v = acc[mi][ni][r] + bb[ni];
        float e = __expf(2.0f * v);
        s += (1.0f - 2.0f / (e + 1.0f)) * wn[ni];
      }
      for (int o = 1; o < 16; o <<= 1) s += __shfl_xor(s, o, 64);
      if (lrow == 0) nred[wc][wr*64 + mi*16 + lk*4 + r] = s;
    }
  }
  __syncthreads();
  if (tid < BM)
    nup[(size_t)nb * M_TOT + m0 + tid] = nred[0][tid] + nred[1][tid];
}

// ---------------- kernel 3: softmax over L per batch ----------------
__global__ __launch_bounds__(512) void softmax_kernel(const float* __restrict__ nup,
                                                      float* __restrict__ alphas) {
  int b = blockIdx.x;
  int l = threadIdx.x;
  int m = b * L_DIM + l;
  float v = 0.f;
  for (int nb = 0; nb < NB_CNT; ++nb) v += nup[(size_t)nb * M_TOT + m];
  __shared__ float smax[8], ssum[8];
  int w = l >> 6, ln = l & 63;
  float mx = v;
  for (int o = 1; o < 64; o <<= 1) mx = fmaxf(mx, __shfl_xor(mx, o, 64));
  if (ln == 0) smax[w] = mx;
  __syncthreads();
  mx = smax[0];
  for (int i = 1; i < 8; ++i) mx = fmaxf(mx, smax[i]);
  float e = __expf(v - mx);
  float sm = e;
  for (int o = 1; o < 64; o <<= 1) sm += __shfl_xor(sm, o, 64);
  if (ln == 0) ssum[w] = sm;
  __syncthreads();
  float tot = 0.f;
  for (int i = 0; i < 8; ++i) tot += ssum[i];
  alphas[m] = e / tot;
}

// ---------------- kernel 4/5: weighted pooling (deterministic 2-stage) ----------------
__global__ __launch_bounds__(256) void pool1_kernel(const float* __restrict__ hs,
                                                    const float* __restrict__ alphas,
                                                    float* __restrict__ part) {
  int b = blockIdx.x >> 3;
  int lc = blockIdx.x & 7;
  int tid = threadIdx.x;
  __shared__ float al[64];
  if (tid < 64) al[tid] = alphas[b * L_DIM + lc*64 + tid];
  __syncthreads();
  const float* xp = hs + ((size_t)b * L_DIM + lc*64) * H_DIM;
  int h0 = tid * 3;
  float s0 = 0.f, s1 = 0.f, s2 = 0.f;
  for (int l = 0; l < 64; ++l) {
    float a = al[l];
    const float* r = xp + (size_t)l * H_DIM + h0;
    s0 += a * r[0]; s1 += a * r[1]; s2 += a * r[2];
  }
  float* dst = part + ((size_t)lc * B_DIM + b) * H_DIM + h0;
  dst[0] = s0; dst[1] = s1; dst[2] = s2;
}

__global__ __launch_bounds__(256) void pool2_kernel(const float* __restrict__ part,
                                                    float* __restrict__ out) {
  int i = blockIdx.x * 256 + threadIdx.x;
  float s = 0.f;
  for (int lc = 0; lc < 8; ++lc) s += part[(size_t)lc * (B_DIM * H_DIM) + i];
  out[i] = s;
}

extern "C" void kernel_launch(void* const* d_in, const int* in_sizes, int n_in,
                              void* d_out, int out_size, void* d_ws, size_t ws_size,
                              hipStream_t stream) {
  const float* hs  = (const float*)d_in[0];
  const float* Wfc = (const float*)d_in[1];
  const float* bfc = (const float*)d_in[2];
  const float* wnu = (const float*)d_in[3];
  float* out = (float*)d_out;
  char* ws = (char*)d_ws;
  _Float16* W16 = (_Float16*)(ws + WS_W16);
  float* nup    = (float*)(ws + WS_NUP);
  float* alphas = (float*)(ws + WS_ALPHA);
  float* part   = (float*)(ws + WS_POOL);

  wconv_kernel<<<NB_CNT * KB_CNT, 256, 0, stream>>>(Wfc, W16);
  if (ws_size >= WS_NEED_IMG) {
    _Float16* Aimg = (_Float16*)(ws + WS_AIMG);
    aconv_kernel<<<MB_CNT * KB_CNT, 256, 0, stream>>>(hs, Aimg);
    gemm_nu_img_kernel<<<MB_CNT * NB_CNT, 256, 0, stream>>>(Aimg, W16, bfc, wnu, nup);
  } else {
    gemm_nu_kernel<<<MB_CNT * NB_CNT, 256, 0, stream>>>(hs, W16, bfc, wnu, nup);
  }
  softmax_kernel<<<B_DIM, 512, 0, stream>>>(nup, alphas);
  pool1_kernel<<<B_DIM * 8, 256, 0, stream>>>(hs, alphas, part);
  pool2_kernel<<<192, 256, 0, stream>>>(part, out);
}

// Round 3
// 100.699 us; speedup vs baseline: 1.2904x; 1.1151x over previous
//
#include <hip/hip_runtime.h>

#define H_DIM 768
#define B_DIM 64
#define L_DIM 512
#define M_TOT (B_DIM*L_DIM)   // 32768
#define BM 128
#define BN 128
#define BK 64
#define NB_CNT (H_DIM/BN)     // 6
#define KB_CNT (H_DIM/BK)     // 12
#define MB_CNT (M_TOT/BM)     // 256
#define TILE_HALFS (BM*BK)    // 8192 halfs = 16KB

typedef _Float16 f16x8 __attribute__((ext_vector_type(8)));
typedef float f32x4 __attribute__((ext_vector_type(4)));

// ws byte offsets
#define WS_W16   0u           // 768*768 halfs = 1179648 B (tiled, swizzle-baked)
#define WS_NUP   1179648u     // 6*32768 f32 = 786432 B
#define WS_ALPHA 1966080u     // 32768 f32
#define WS_POOL  2097152u     // 8*64*768 f32 = 1572864 B
#define WS_AIMG  3670016u     // 32768*768 halfs = 50331648 B (tiled, swizzle-baked)
#define WS_NEED_IMG (WS_AIMG + (size_t)M_TOT*H_DIM*2)

__device__ __forceinline__ void gload_lds16(const void* g, void* l) {
  __builtin_amdgcn_global_load_lds((const __attribute__((address_space(1))) void*)g,
                                   (__attribute__((address_space(3))) void*)l, 16, 0, 0);
}

__device__ __forceinline__ f16x8 cvt8(const float* src) {
  f32x4 x0 = *(const f32x4*)src;
  f32x4 x1 = *(const f32x4*)(src + 4);
  f16x8 h;
  h[0]=(_Float16)x0[0]; h[1]=(_Float16)x0[1]; h[2]=(_Float16)x0[2]; h[3]=(_Float16)x0[3];
  h[4]=(_Float16)x1[0]; h[5]=(_Float16)x1[1]; h[6]=(_Float16)x1[2]; h[7]=(_Float16)x1[3];
  return h;
}

// tanh(v) = 1 - 2/(exp(2v)+1); exp(2v) = exp2(2.885390...*v). inf/0 limits give +-1.
__device__ __forceinline__ float fast_tanh(float v) {
  float e = __builtin_amdgcn_exp2f(v * 2.8853900817779268f);
  return 1.0f - 2.0f * __builtin_amdgcn_rcpf(e + 1.0f);
}

// ---------------- kernel 1: W_fc fp32 -> fp16, tiled + swizzle-baked ----------------
// Tile t = nb*KB_CNT + kb holds BN x BK halfs in LDS-image order:
//   image[row*BK + sp*8 + j] = W_fc[nb*BN+row][kb*BK + (sp^(row&7))*8 + j]
__global__ __launch_bounds__(256) void wconv_kernel(const float* __restrict__ Wfc,
                                                    _Float16* __restrict__ W16) {
  int t = blockIdx.x;             // 0..71
  int nb = t / KB_CNT, kb = t % KB_CNT;
  for (int i = 0; i < 4; ++i) {
    int u = threadIdx.x + i * 256;        // (row, phys slot)
    int row = u >> 3, sp = u & 7;
    int sl = sp ^ (row & 7);
    *(f16x8*)(W16 + (size_t)t*TILE_HALFS + u*8) =
        cvt8(Wfc + (size_t)(nb*BN + row)*H_DIM + kb*BK + sl*8);
  }
}

// ---------------- kernel 1b: hidden_states fp32 -> fp16 tiled image ----------------
__global__ __launch_bounds__(256) void aconv_kernel(const float* __restrict__ A,
                                                    _Float16* __restrict__ img) {
  int t = blockIdx.x;             // 0..3071
  int mb = t / KB_CNT, kb = t % KB_CNT;
  _Float16* tile = img + (size_t)t * TILE_HALFS;
  for (int i = 0; i < 4; ++i) {
    int u = threadIdx.x + i * 256;
    int row = u >> 3, sp = u & 7;
    int sl = sp ^ (row & 7);
    *(f16x8*)(tile + u*8) =
        cvt8(A + (size_t)(mb*BM + row)*H_DIM + kb*BK + sl*8);
  }
}

// ---------------- GEMM helpers ----------------
__device__ __forceinline__ void stage_tile(const _Float16* at, const _Float16* wt,
                                           _Float16* LA, _Float16* LB, int wv, int ln) {
#pragma unroll
  for (int i = 0; i < 4; ++i) {
    int e = i*2048 + wv*512 + ln*8;       // bytes = i*4096 + wv*1024 + ln*16, linear per wave
    gload_lds16(at + e, LA + e);
    gload_lds16(wt + e, LB + e);
  }
}

__device__ __forceinline__ void compute_tile(const _Float16* LA, const _Float16* LB,
                                             f32x4 acc[4][4], int wr, int wc,
                                             int lrow, int lk) {
#pragma unroll
  for (int kk = 0; kk < 2; ++kk) {
    f16x8 af[4], bf[4];
    int s = kk*4 + lk;
#pragma unroll
    for (int mi = 0; mi < 4; ++mi) {
      int r = wr*64 + mi*16 + lrow;
      af[mi] = *(const f16x8*)(LA + r*BK + ((s ^ (r & 7)) * 8));
    }
#pragma unroll
    for (int ni = 0; ni < 4; ++ni) {
      int r = wc*64 + ni*16 + lrow;
      bf[ni] = *(const f16x8*)(LB + r*BK + ((s ^ (r & 7)) * 8));
    }
#pragma unroll
    for (int mi = 0; mi < 4; ++mi)
#pragma unroll
      for (int ni = 0; ni < 4; ++ni)
        acc[mi][ni] = __builtin_amdgcn_mfma_f32_16x16x32_f16(af[mi], bf[ni], acc[mi][ni], 0, 0, 0);
  }
}

// ---------------- kernel 2: 2-phase double-buffered GEMM + tanh + dot(W_nu) ----------------
// STAGE(t+1) issued BEFORE compute(t); single barrier per K-step. The compiler's
// vmcnt(0)-before-s_barrier then lands after ~400cyc of ds_read+MFMA -> latency hidden.
__global__ __launch_bounds__(256) void gemm_nu_img_kernel(const _Float16* __restrict__ Aimg,
                                                          const _Float16* __restrict__ W16,
                                                          const float* __restrict__ bfc,
                                                          const float* __restrict__ wnu,
                                                          float* __restrict__ nup) {
  __shared__ __align__(16) _Float16 lsA0[TILE_HALFS];
  __shared__ __align__(16) _Float16 lsB0[TILE_HALFS];
  __shared__ __align__(16) _Float16 lsA1[TILE_HALFS];
  __shared__ __align__(16) _Float16 lsB1[TILE_HALFS];
  __shared__ float nred[2][BM];

  int bid = blockIdx.x;
  int mb = bid & (MB_CNT - 1);    // all CUs sweep one nb-pass together -> A-image L3 reuse
  int nb = bid >> 8;
  int m0 = mb * BM, n0 = nb * BN;
  int tid = threadIdx.x;
  int wv = tid >> 6, ln = tid & 63;
  int wr = wv >> 1, wc = wv & 1;
  int lrow = ln & 15, lk = ln >> 4;

  f32x4 acc[4][4] = {};
  const _Float16* abase = Aimg + (size_t)(mb * KB_CNT) * TILE_HALFS;
  const _Float16* wbase = W16 + (size_t)(nb * KB_CNT) * TILE_HALFS;

  // epilogue constants, loaded early
  float wn[4], bb[4];
#pragma unroll
  for (int ni = 0; ni < 4; ++ni) {
    int c = n0 + wc*64 + ni*16 + lrow;    // C/D col = lane&15 (m89-verified)
    wn[ni] = wnu[c];
    bb[ni] = bfc[c];
  }

  stage_tile(abase, wbase, lsA0, lsB0, wv, ln);
  __syncthreads();

  for (int kb2 = 0; kb2 < 6; ++kb2) {
    int kb = kb2 * 2;
    stage_tile(abase + (size_t)(kb+1)*TILE_HALFS, wbase + (size_t)(kb+1)*TILE_HALFS,
               lsA1, lsB1, wv, ln);
    compute_tile(lsA0, lsB0, acc, wr, wc, lrow, lk);
    __syncthreads();                      // drains stage->buf1 under the compute above
    if (kb2 < 5)
      stage_tile(abase + (size_t)(kb+2)*TILE_HALFS, wbase + (size_t)(kb+2)*TILE_HALFS,
                 lsA0, lsB0, wv, ln);
    compute_tile(lsA1, lsB1, acc, wr, wc, lrow, lk);
    __syncthreads();
  }

  // epilogue: tanh(acc+b)*wnu, reduce over this block's 128 n-columns
#pragma unroll
  for (int mi = 0; mi < 4; ++mi) {
#pragma unroll
    for (int r = 0; r < 4; ++r) {
      float s = 0.f;
#pragma unroll
      for (int ni = 0; ni < 4; ++ni)
        s = fmaf(fast_tanh(acc[mi][ni][r] + bb[ni]), wn[ni], s);
      for (int o = 1; o < 16; o <<= 1) s += __shfl_xor(s, o, 64);
      if (lrow == 0) nred[wc][wr*64 + mi*16 + lk*4 + r] = s;  // row = (lane>>4)*4+reg
    }
  }
  __syncthreads();
  if (tid < BM)
    nup[(size_t)nb * M_TOT + m0 + tid] = nred[0][tid] + nred[1][tid];
}

// ---------------- fallback GEMM (fp32 A, in-kernel convert) ----------------
__global__ __launch_bounds__(256) void gemm_nu_kernel(const float* __restrict__ A,
                                                      const _Float16* __restrict__ W16,
                                                      const float* __restrict__ bfc,
                                                      const float* __restrict__ wnu,
                                                      float* __restrict__ nup) {
  __shared__ __align__(16) _Float16 lsA[TILE_HALFS];
  __shared__ __align__(16) _Float16 lsB[TILE_HALFS];
  __shared__ float nred[2][BM];

  int bid = blockIdx.x;
  int nb = bid % NB_CNT;
  int mb = bid / NB_CNT;
  int m0 = mb * BM, n0 = nb * BN;
  int tid = threadIdx.x;
  int wv = tid >> 6, ln = tid & 63;
  int wr = wv >> 1, wc = wv & 1;
  int lrow = ln & 15, lk = ln >> 4;

  f32x4 acc[4][4] = {};
  const _Float16* wbase = W16 + (size_t)(nb * KB_CNT) * TILE_HALFS;

  for (int kb = 0; kb < KB_CNT; ++kb) {
    const _Float16* wt = wbase + (size_t)kb * TILE_HALFS;
    for (int i = 0; i < 4; ++i) {
      int e = i*2048 + wv*512 + ln*8;
      gload_lds16(wt + e, lsB + e);
    }
    for (int i = 0; i < 4; ++i) {
      int u = tid + i * 256;
      int row = u >> 3, sl = u & 7;
      *(f16x8*)(lsA + row*BK + ((sl ^ (row & 7)) * 8)) =
          cvt8(A + (size_t)(m0 + row) * H_DIM + kb*BK + sl*8);
    }
    __syncthreads();
    compute_tile(lsA, lsB, acc, wr, wc, lrow, lk);
    __syncthreads();
  }

  float wn[4], bb[4];
  for (int ni = 0; ni < 4; ++ni) {
    int c = n0 + wc*64 + ni*16 + lrow;
    wn[ni] = wnu[c];
    bb[ni] = bfc[c];
  }
  for (int mi = 0; mi < 4; ++mi) {
    for (int r = 0; r < 4; ++r) {
      float s = 0.f;
      for (int ni = 0; ni < 4; ++ni)
        s = fmaf(fast_tanh(acc[mi][ni][r] + bb[ni]), wn[ni], s);
      for (int o = 1; o < 16; o <<= 1) s += __shfl_xor(s, o, 64);
      if (lrow == 0) nred[wc][wr*64 + mi*16 + lk*4 + r] = s;
    }
  }
  __syncthreads();
  if (tid < BM)
    nup[(size_t)nb * M_TOT + m0 + tid] = nred[0][tid] + nred[1][tid];
}

// ---------------- kernel 3: softmax over L per batch ----------------
__global__ __launch_bounds__(512) void softmax_kernel(const float* __restrict__ nup,
                                                      float* __restrict__ alphas) {
  int b = blockIdx.x;
  int l = threadIdx.x;
  int m = b * L_DIM + l;
  float v = 0.f;
  for (int nb = 0; nb < NB_CNT; ++nb) v += nup[(size_t)nb * M_TOT + m];
  __shared__ float smax[8], ssum[8];
  int w = l >> 6, ln = l & 63;
  float mx = v;
  for (int o = 1; o < 64; o <<= 1) mx = fmaxf(mx, __shfl_xor(mx, o, 64));
  if (ln == 0) smax[w] = mx;
  __syncthreads();
  mx = smax[0];
  for (int i = 1; i < 8; ++i) mx = fmaxf(mx, smax[i]);
  float e = __expf(v - mx);
  float sm = e;
  for (int o = 1; o < 64; o <<= 1) sm += __shfl_xor(sm, o, 64);
  if (ln == 0) ssum[w] = sm;
  __syncthreads();
  float tot = 0.f;
  for (int i = 0; i < 8; ++i) tot += ssum[i];
  alphas[m] = e / tot;
}

// ---------------- kernel 4/5: weighted pooling (deterministic 2-stage) ----------------
__global__ __launch_bounds__(256) void pool1_kernel(const float* __restrict__ hs,
                                                    const float* __restrict__ alphas,
                                                    float* __restrict__ part) {
  int b = blockIdx.x >> 3;
  int lc = blockIdx.x & 7;
  int tid = threadIdx.x;
  __shared__ float al[64];
  if (tid < 64) al[tid] = alphas[b * L_DIM + lc*64 + tid];
  __syncthreads();
  const float* xp = hs + ((size_t)b * L_DIM + lc*64) * H_DIM;
  int h0 = tid * 3;
  float s0 = 0.f, s1 = 0.f, s2 = 0.f;
  for (int l = 0; l < 64; ++l) {
    float a = al[l];
    const float* r = xp + (size_t)l * H_DIM + h0;
    s0 += a * r[0]; s1 += a * r[1]; s2 += a * r[2];
  }
  float* dst = part + ((size_t)lc * B_DIM + b) * H_DIM + h0;
  dst[0] = s0; dst[1] = s1; dst[2] = s2;
}

__global__ __launch_bounds__(256) void pool2_kernel(const float* __restrict__ part,
                                                    float* __restrict__ out) {
  int i = blockIdx.x * 256 + threadIdx.x;
  float s = 0.f;
  for (int lc = 0; lc < 8; ++lc) s += part[(size_t)lc * (B_DIM * H_DIM) + i];
  out[i] = s;
}

extern "C" void kernel_launch(void* const* d_in, const int* in_sizes, int n_in,
                              void* d_out, int out_size, void* d_ws, size_t ws_size,
                              hipStream_t stream) {
  const float* hs  = (const float*)d_in[0];
  const float* Wfc = (const float*)d_in[1];
  const float* bfc = (const float*)d_in[2];
  const float* wnu = (const float*)d_in[3];
  float* out = (float*)d_out;
  char* ws = (char*)d_ws;
  _Float16* W16 = (_Float16*)(ws + WS_W16);
  float* nup    = (float*)(ws + WS_NUP);
  float* alphas = (float*)(ws + WS_ALPHA);
  float* part   = (float*)(ws + WS_POOL);

  wconv_kernel<<<NB_CNT * KB_CNT, 256, 0, stream>>>(Wfc, W16);
  if (ws_size >= WS_NEED_IMG) {
    _Float16* Aimg = (_Float16*)(ws + WS_AIMG);
    aconv_kernel<<<MB_CNT * KB_CNT, 256, 0, stream>>>(hs, Aimg);
    gemm_nu_img_kernel<<<MB_CNT * NB_CNT, 256, 0, stream>>>(Aimg, W16, bfc, wnu, nup);
  } else {
    gemm_nu_kernel<<<MB_CNT * NB_CNT, 256, 0, stream>>>(hs, W16, bfc, wnu, nup);
  }
  softmax_kernel<<<B_DIM, 512, 0, stream>>>(nup, alphas);
  pool1_kernel<<<B_DIM * 8, 256, 0, stream>>>(hs, alphas, part);
  pool2_kernel<<<192, 256, 0, stream>>>(part, out);
}